// Round 5
// baseline (454.004 us; speedup 1.0000x reference)
//
#include <hip/hip_runtime.h>

#define N_NODES 50000
#define NEDGE   800000
#define D       128
#define EPS     1e-5f
#define MTILE   32
#define TPB_TILES 3
#define NTILES  1563            // ceil(50000/32), == 3*521
#define NB_MM   521

typedef __attribute__((ext_vector_type(8))) short bf16x8;
typedef __attribute__((ext_vector_type(4))) float f32x4;
typedef __attribute__((ext_vector_type(8))) unsigned short u16x8;

// fp32 -> bf16 (RNE) as ushort bits
__device__ inline uint32_t bfhi(float f) {
    uint32_t u = __float_as_uint(f);
    u += 0x7fffu + ((u >> 16) & 1u);
    return u >> 16;
}
__device__ inline float bff(uint32_t h) { return __uint_as_float(h << 16); }

// ---------------- degree count ----------------
__global__ __launch_bounds__(256) void k_deg(const int* __restrict__ dst,
                                             int* __restrict__ degi) {
    int e = blockIdx.x * 256 + threadIdx.x;
    if (e < NEDGE) atomicAdd(&degi[dst[e]], 1);
}

// ---------------- exclusive scan (3 kernels) ----------------
__global__ __launch_bounds__(256) void k_scan1(const int* __restrict__ degi,
                                               int* __restrict__ offs,
                                               int* __restrict__ bsum) {
    __shared__ int s[256];
    int tid = threadIdx.x;
    int i = blockIdx.x * 256 + tid;
    int v = (i < N_NODES) ? degi[i] : 0;
    s[tid] = v;
    __syncthreads();
    for (int d = 1; d < 256; d <<= 1) {
        int t = (tid >= d) ? s[tid - d] : 0;
        __syncthreads();
        s[tid] += t;
        __syncthreads();
    }
    if (i < N_NODES) offs[i] = s[tid] - v;   // exclusive
    if (tid == 255) bsum[blockIdx.x] = s[255];
}

__global__ __launch_bounds__(256) void k_scan2(int* __restrict__ bsum, int nb) {
    __shared__ int s[256];
    int tid = threadIdx.x;
    int v = (tid < nb) ? bsum[tid] : 0;
    s[tid] = v;
    __syncthreads();
    for (int d = 1; d < 256; d <<= 1) {
        int t = (tid >= d) ? s[tid - d] : 0;
        __syncthreads();
        s[tid] += t;
        __syncthreads();
    }
    if (tid < nb) bsum[tid] = s[tid] - v;    // exclusive block offsets
}

__global__ __launch_bounds__(256) void k_scan3(const int* __restrict__ degi,
                                               const int* __restrict__ bsum,
                                               int* __restrict__ offs,
                                               int* __restrict__ cursor,
                                               float* __restrict__ invdeg) {
    int i = blockIdx.x * 256 + threadIdx.x;
    if (i < N_NODES) {
        int o = offs[i] + bsum[blockIdx.x];
        offs[i] = o;
        cursor[i] = o;
        int dg = degi[i];
        invdeg[i] = 1.0f / (float)(dg > 0 ? dg : 1);
    }
    if (i == 0 && blockIdx.x == 0) offs[N_NODES] = NEDGE;
}

// ---------------- CSR bucket fill ----------------
__global__ __launch_bounds__(256) void k_fill(const int* __restrict__ src,
                                              const int* __restrict__ dst,
                                              int* __restrict__ cursor,
                                              int* __restrict__ csr) {
    int e = blockIdx.x * 256 + threadIdx.x;
    if (e < NEDGE) {
        int p = atomicAdd(&cursor[dst[e]], 1);
        csr[p] = src[e];
    }
}

// ---------------- fp32 -> bf16(hi) plane (for layer-1 gather) ----------------
__global__ __launch_bounds__(256) void k_tobf16(const float* __restrict__ X,
                                                unsigned short* __restrict__ XB) {
    int t = blockIdx.x * 256 + threadIdx.x;
    if (t >= (N_NODES * D) / 8) return;
    const float* p = X + (size_t)t * 8;
    float4 a = *reinterpret_cast<const float4*>(p);
    float4 b = *reinterpret_cast<const float4*>(p + 4);
    u16x8 o;
    o[0] = (unsigned short)bfhi(a.x); o[1] = (unsigned short)bfhi(a.y);
    o[2] = (unsigned short)bfhi(a.z); o[3] = (unsigned short)bfhi(a.w);
    o[4] = (unsigned short)bfhi(b.x); o[5] = (unsigned short)bfhi(b.y);
    o[6] = (unsigned short)bfhi(b.z); o[7] = (unsigned short)bfhi(b.w);
    *reinterpret_cast<u16x8*>(XB + (size_t)t * 8) = o;
}

// ---------------- mean aggregation: gather bf16(hi) rows over CSR ----------------
// 16 nodes per 256-thread block; 16 lanes per node; 2-edge unroll for MLP.
__global__ __launch_bounds__(256) void k_agg(const unsigned short* __restrict__ XB,
                                             const int* __restrict__ offs,
                                             const int* __restrict__ csr,
                                             const float* __restrict__ invdeg,
                                             const float* __restrict__ bnscale,
                                             const float* __restrict__ bnshift,
                                             int useBn,
                                             float* __restrict__ HN) {
    int n = blockIdx.x * 16 + (threadIdx.x >> 4);
    if (n >= N_NODES) return;
    int c = (threadIdx.x & 15) * 8;

    float sc[8], sh[8];
    if (useBn) {
        float4 s0 = *reinterpret_cast<const float4*>(bnscale + c);
        float4 s1 = *reinterpret_cast<const float4*>(bnscale + c + 4);
        float4 h0 = *reinterpret_cast<const float4*>(bnshift + c);
        float4 h1 = *reinterpret_cast<const float4*>(bnshift + c + 4);
        sc[0] = s0.x; sc[1] = s0.y; sc[2] = s0.z; sc[3] = s0.w;
        sc[4] = s1.x; sc[5] = s1.y; sc[6] = s1.z; sc[7] = s1.w;
        sh[0] = h0.x; sh[1] = h0.y; sh[2] = h0.z; sh[3] = h0.w;
        sh[4] = h1.x; sh[5] = h1.y; sh[6] = h1.z; sh[7] = h1.w;
    }

    int e0 = offs[n], e1 = offs[n + 1];
    float a0[8], a1[8];
#pragma unroll
    for (int i = 0; i < 8; ++i) { a0[i] = 0.f; a1[i] = 0.f; }

    int e = e0;
    for (; e + 2 <= e1; e += 2) {
        int s0i = csr[e], s1i = csr[e + 1];
        u16x8 v0 = *reinterpret_cast<const u16x8*>(XB + (size_t)s0i * D + c);
        u16x8 v1 = *reinterpret_cast<const u16x8*>(XB + (size_t)s1i * D + c);
        if (useBn) {
#pragma unroll
            for (int i = 0; i < 8; ++i) {
                a0[i] += fmaxf(bff((unsigned short)v0[i]) * sc[i] + sh[i], 0.f);
                a1[i] += fmaxf(bff((unsigned short)v1[i]) * sc[i] + sh[i], 0.f);
            }
        } else {
#pragma unroll
            for (int i = 0; i < 8; ++i) {
                a0[i] += bff((unsigned short)v0[i]);
                a1[i] += bff((unsigned short)v1[i]);
            }
        }
    }
    if (e < e1) {
        int s0i = csr[e];
        u16x8 v0 = *reinterpret_cast<const u16x8*>(XB + (size_t)s0i * D + c);
        if (useBn) {
#pragma unroll
            for (int i = 0; i < 8; ++i)
                a0[i] += fmaxf(bff((unsigned short)v0[i]) * sc[i] + sh[i], 0.f);
        } else {
#pragma unroll
            for (int i = 0; i < 8; ++i)
                a0[i] += bff((unsigned short)v0[i]);
        }
    }
    float id = invdeg[n];
    float4 o0 = {(a0[0] + a1[0]) * id, (a0[1] + a1[1]) * id,
                 (a0[2] + a1[2]) * id, (a0[3] + a1[3]) * id};
    float4 o1 = {(a0[4] + a1[4]) * id, (a0[5] + a1[5]) * id,
                 (a0[6] + a1[6]) * id, (a0[7] + a1[7]) * id};
    *reinterpret_cast<float4*>(HN + (size_t)n * D + c) = o0;
    *reinterpret_cast<float4*>(HN + (size_t)n * D + c + 4) = o1;
}

// ---------------- weight prep: transpose + split fp32 -> bf16 hi/lo ----------------
__global__ __launch_bounds__(256) void k_wprep(const float* __restrict__ W0,
                                               const float* __restrict__ W1,
                                               const float* __restrict__ W2,
                                               const float* __restrict__ W3,
                                               const float* __restrict__ W4,
                                               const float* __restrict__ W5,
                                               unsigned short* __restrict__ wt) {
    int mat = blockIdx.x >> 6;
    const float* srcs[6] = {W0, W1, W2, W3, W4, W5};
    const float* W = srcs[mat];
    int t = (blockIdx.x & 63) * 256 + threadIdx.x;
    int k = t >> 7;
    int n = t & 127;
    float w = W[k * 128 + n];
    uint32_t h = bfhi(w);
    uint32_t l = bfhi(w - bff(h));
    unsigned short* base = wt + (size_t)mat * 32768;
    base[n * 128 + k] = (unsigned short)h;
    base[16384 + n * 128 + k] = (unsigned short)l;
}

// ---------------- MFMA GEMM, pipelined over 3 M-tiles of 32 rows ----------------
// 256 threads (4 waves); wave owns 32 output cols (2 col-blocks of 16).
// LDS: 4 planes (Xhi,Xlo,Ahi,Alo) x [32 rows][256B], XOR-swizzled (row&7)<<4.
// Per tile: issue next tile's global loads -> regs, MFMA current, barrier,
// convert+write next -> LDS, barrier.  BN stats accumulated across tiles.
__global__ __launch_bounds__(256, 2) void k_mm(const float* __restrict__ Xf,
                                               const unsigned short* __restrict__ Xhi,
                                               const unsigned short* __restrict__ Xlo,
                                               const float* __restrict__ HN,
                                               const unsigned short* __restrict__ WsT,
                                               const unsigned short* __restrict__ WnT,
                                               const float* __restrict__ bias,
                                               const float* __restrict__ bnscale,
                                               const float* __restrict__ bnshift,
                                               int mode,   // 0: Xf raw; 1: Xhi/Xlo + BN+ReLU
                                               float* __restrict__ OUTf,
                                               unsigned short* __restrict__ OUThi,
                                               unsigned short* __restrict__ OUTlo,
                                               int outFp32,
                                               int doStats,
                                               float* __restrict__ sums) {
    __shared__ __align__(16) unsigned char smem[4 * 8192];

    const int tid = threadIdx.x;
    const int lane = tid & 63;
    const int wave = tid >> 6;
    const int mlo = lane & 15;
    const int g = lane >> 4;
    const int ks = tid & 15;        // staging k-slot (same for both units)
    const int srow = tid >> 4;      // staging row (unit 0); unit 1 = +16

    // ---- B fragments [cb][kc] + bias ----
    bf16x8 wsh[2][4], wsl[2][4], wnh[2][4], wnl[2][4];
    int colcb[2];
    float bcol[2];
#pragma unroll
    for (int cb = 0; cb < 2; ++cb) {
        int col = (wave << 5) + (cb << 4) + mlo;
        colcb[cb] = col;
        bcol[cb] = bias[col];
#pragma unroll
        for (int kc = 0; kc < 4; ++kc) {
            int ko = kc * 32 + g * 8;
            wsh[cb][kc] = *reinterpret_cast<const bf16x8*>(WsT + (size_t)col * 128 + ko);
            wsl[cb][kc] = *reinterpret_cast<const bf16x8*>(WsT + 16384 + (size_t)col * 128 + ko);
            wnh[cb][kc] = *reinterpret_cast<const bf16x8*>(WnT + (size_t)col * 128 + ko);
            wnl[cb][kc] = *reinterpret_cast<const bf16x8*>(WnT + 16384 + (size_t)col * 128 + ko);
        }
    }

    // ---- BN scale/shift for this thread's k-slot (mode 1 only) ----
    float sc8[8], sh8[8];
    if (mode == 1) {
        float4 s0 = *reinterpret_cast<const float4*>(bnscale + ks * 8);
        float4 s1 = *reinterpret_cast<const float4*>(bnscale + ks * 8 + 4);
        float4 h0 = *reinterpret_cast<const float4*>(bnshift + ks * 8);
        float4 h1 = *reinterpret_cast<const float4*>(bnshift + ks * 8 + 4);
        sc8[0] = s0.x; sc8[1] = s0.y; sc8[2] = s0.z; sc8[3] = s0.w;
        sc8[4] = s1.x; sc8[5] = s1.y; sc8[6] = s1.z; sc8[7] = s1.w;
        sh8[0] = h0.x; sh8[1] = h0.y; sh8[2] = h0.z; sh8[3] = h0.w;
        sh8[4] = h1.x; sh8[5] = h1.y; sh8[6] = h1.z; sh8[7] = h1.w;
    }

    // ---- staging registers (2 units/thread) ----
    float4 rx0[2], rx1[2], rh0[2], rh1[2];
    u16x8 rhi[2], rlo[2];

    auto stage_load = [&](int t) {
#pragma unroll
        for (int uu = 0; uu < 2; ++uu) {
            int grow = t * MTILE + srow + uu * 16;
            if (grow < N_NODES) {
                const float* ap = HN + (size_t)grow * D + ks * 8;
                rh0[uu] = *reinterpret_cast<const float4*>(ap);
                rh1[uu] = *reinterpret_cast<const float4*>(ap + 4);
                if (mode == 0) {
                    const float* xp = Xf + (size_t)grow * D + ks * 8;
                    rx0[uu] = *reinterpret_cast<const float4*>(xp);
                    rx1[uu] = *reinterpret_cast<const float4*>(xp + 4);
                } else {
                    rhi[uu] = *reinterpret_cast<const u16x8*>(Xhi + (size_t)grow * D + ks * 8);
                    rlo[uu] = *reinterpret_cast<const u16x8*>(Xlo + (size_t)grow * D + ks * 8);
                }
            } else {
                float4 z = {0.f, 0.f, 0.f, 0.f};
                rh0[uu] = z; rh1[uu] = z;
                if (mode == 0) { rx0[uu] = z; rx1[uu] = z; }
                else {
                    u16x8 zu = {0, 0, 0, 0, 0, 0, 0, 0};
                    rhi[uu] = zu; rlo[uu] = zu;
                }
            }
        }
    };

    auto stage_write = [&]() {
#pragma unroll
        for (int uu = 0; uu < 2; ++uu) {
            int r = srow + uu * 16;
            float f[8], a[8];
            if (mode == 0) {
                f[0] = rx0[uu].x; f[1] = rx0[uu].y; f[2] = rx0[uu].z; f[3] = rx0[uu].w;
                f[4] = rx1[uu].x; f[5] = rx1[uu].y; f[6] = rx1[uu].z; f[7] = rx1[uu].w;
            } else {
#pragma unroll
                for (int i = 0; i < 8; ++i) {
                    float v = bff((unsigned short)rhi[uu][i]) + bff((unsigned short)rlo[uu][i]);
                    f[i] = fmaxf(v * sc8[i] + sh8[i], 0.f);
                }
            }
            a[0] = rh0[uu].x; a[1] = rh0[uu].y; a[2] = rh0[uu].z; a[3] = rh0[uu].w;
            a[4] = rh1[uu].x; a[5] = rh1[uu].y; a[6] = rh1[uu].z; a[7] = rh1[uu].w;

            int base = r * 256 + ((ks * 16) ^ ((r & 7) << 4));
            uint32_t h8[8];
            int4 vhi, vlo;
#pragma unroll
            for (int i = 0; i < 8; ++i) h8[i] = bfhi(f[i]);
            vhi.x = h8[0] | (h8[1] << 16); vhi.y = h8[2] | (h8[3] << 16);
            vhi.z = h8[4] | (h8[5] << 16); vhi.w = h8[6] | (h8[7] << 16);
            {
                uint32_t l0 = bfhi(f[0] - bff(h8[0])), l1 = bfhi(f[1] - bff(h8[1]));
                uint32_t l2 = bfhi(f[2] - bff(h8[2])), l3 = bfhi(f[3] - bff(h8[3]));
                uint32_t l4 = bfhi(f[4] - bff(h8[4])), l5 = bfhi(f[5] - bff(h8[5]));
                uint32_t l6 = bfhi(f[6] - bff(h8[6])), l7 = bfhi(f[7] - bff(h8[7]));
                vlo.x = l0 | (l1 << 16); vlo.y = l2 | (l3 << 16);
                vlo.z = l4 | (l5 << 16); vlo.w = l6 | (l7 << 16);
            }
            *reinterpret_cast<int4*>(smem + 0 * 8192 + base) = vhi;
            *reinterpret_cast<int4*>(smem + 1 * 8192 + base) = vlo;
#pragma unroll
            for (int i = 0; i < 8; ++i) h8[i] = bfhi(a[i]);
            vhi.x = h8[0] | (h8[1] << 16); vhi.y = h8[2] | (h8[3] << 16);
            vhi.z = h8[4] | (h8[5] << 16); vhi.w = h8[6] | (h8[7] << 16);
            {
                uint32_t l0 = bfhi(a[0] - bff(h8[0])), l1 = bfhi(a[1] - bff(h8[1]));
                uint32_t l2 = bfhi(a[2] - bff(h8[2])), l3 = bfhi(a[3] - bff(h8[3]));
                uint32_t l4 = bfhi(a[4] - bff(h8[4])), l5 = bfhi(a[5] - bff(h8[5]));
                uint32_t l6 = bfhi(a[6] - bff(h8[6])), l7 = bfhi(a[7] - bff(h8[7]));
                vlo.x = l0 | (l1 << 16); vlo.y = l2 | (l3 << 16);
                vlo.z = l4 | (l5 << 16); vlo.w = l6 | (l7 << 16);
            }
            *reinterpret_cast<int4*>(smem + 2 * 8192 + base) = vhi;
            *reinterpret_cast<int4*>(smem + 3 * 8192 + base) = vlo;
        }
    };

    const int t0 = blockIdx.x * TPB_TILES;
    float cs[2] = {0.f, 0.f}, cq[2] = {0.f, 0.f};

    // prologue
    stage_load(t0);
    stage_write();
    __syncthreads();

    for (int tt = 0; tt < TPB_TILES; ++tt) {
        const int row0 = (t0 + tt) * MTILE;
        if (tt + 1 < TPB_TILES) stage_load(t0 + tt + 1);   // issue early (T14)

        f32x4 acc[2][2];
#pragma unroll
        for (int s = 0; s < 2; ++s)
#pragma unroll
            for (int cb = 0; cb < 2; ++cb) acc[s][cb] = (f32x4){0.f, 0.f, 0.f, 0.f};

#pragma unroll
        for (int kc = 0; kc < 4; ++kc) {
            int ksr = kc * 4 + g;
            int koff = (ksr * 16) ^ ((mlo & 7) << 4);
#pragma unroll
            for (int s = 0; s < 2; ++s) {
                int ad = (s * 16 + mlo) * 256 + koff;
                bf16x8 xh = *reinterpret_cast<const bf16x8*>(smem + 0 * 8192 + ad);
                bf16x8 xl = *reinterpret_cast<const bf16x8*>(smem + 1 * 8192 + ad);
                bf16x8 ah = *reinterpret_cast<const bf16x8*>(smem + 2 * 8192 + ad);
                bf16x8 al = *reinterpret_cast<const bf16x8*>(smem + 3 * 8192 + ad);
#pragma unroll
                for (int cb = 0; cb < 2; ++cb) {
                    acc[s][cb] = __builtin_amdgcn_mfma_f32_16x16x32_bf16(xh, wsh[cb][kc], acc[s][cb], 0, 0, 0);
                    acc[s][cb] = __builtin_amdgcn_mfma_f32_16x16x32_bf16(xh, wsl[cb][kc], acc[s][cb], 0, 0, 0);
                    acc[s][cb] = __builtin_amdgcn_mfma_f32_16x16x32_bf16(xl, wsh[cb][kc], acc[s][cb], 0, 0, 0);
                    acc[s][cb] = __builtin_amdgcn_mfma_f32_16x16x32_bf16(ah, wnh[cb][kc], acc[s][cb], 0, 0, 0);
                    acc[s][cb] = __builtin_amdgcn_mfma_f32_16x16x32_bf16(ah, wnl[cb][kc], acc[s][cb], 0, 0, 0);
                    acc[s][cb] = __builtin_amdgcn_mfma_f32_16x16x32_bf16(al, wnh[cb][kc], acc[s][cb], 0, 0, 0);
                }
            }
        }

        // epilogue: bias, store, stats accumulate
#pragma unroll
        for (int s = 0; s < 2; ++s)
#pragma unroll
            for (int cb = 0; cb < 2; ++cb)
#pragma unroll
                for (int r = 0; r < 4; ++r) {
                    int grow = row0 + s * 16 + g * 4 + r;
                    if (grow < N_NODES) {
                        float v = acc[s][cb][r] + bcol[cb];
                        if (outFp32) {
                            OUTf[(size_t)grow * D + colcb[cb]] = v;
                        } else {
                            uint32_t h = bfhi(v);
                            OUThi[(size_t)grow * D + colcb[cb]] = (unsigned short)h;
                            OUTlo[(size_t)grow * D + colcb[cb]] = (unsigned short)bfhi(v - bff(h));
                        }
                        cs[cb] += v; cq[cb] += v * v;
                    }
                }

        if (tt + 1 < TPB_TILES) {
            __syncthreads();      // all waves done reading LDS
            stage_write();        // overwrite with next tile (loads complete by now)
            __syncthreads();      // writes visible
        }
    }

    if (doStats) {
#pragma unroll
        for (int cb = 0; cb < 2; ++cb) {
            float s = cs[cb], q = cq[cb];
            s += __shfl_xor(s, 16); s += __shfl_xor(s, 32);
            q += __shfl_xor(q, 16); q += __shfl_xor(q, 32);
            if (lane < 16) {
                atomicAdd(&sums[colcb[cb]], s);
                atomicAdd(&sums[128 + colcb[cb]], q);
            }
        }
    }
}

// ---------------- BN finalize: per-column scale/shift ----------------
__global__ void k_bnfin(const float* __restrict__ sums,
                        const float* __restrict__ gamma,
                        const float* __restrict__ beta,
                        float* __restrict__ scale,
                        float* __restrict__ shift) {
    int c = threadIdx.x;  // 128 threads
    const float invN = 1.0f / (float)N_NODES;
    float mu = sums[c] * invN;
    float var = sums[128 + c] * invN - mu * mu;
    float s = gamma[c] * rsqrtf(var + EPS);
    scale[c] = s;
    shift[c] = beta[c] - mu * s;
}

// ---------------- launch ----------------
extern "C" void kernel_launch(void* const* d_in, const int* in_sizes, int n_in,
                              void* d_out, int out_size, void* d_ws, size_t ws_size,
                              hipStream_t stream) {
    const float* x   = (const float*)d_in[0];
    const int*   src = (const int*)d_in[1];
    const int*   dst = (const int*)d_in[2];
    const float* Ws1 = (const float*)d_in[3];
    const float* Wn1 = (const float*)d_in[4];
    const float* b1  = (const float*)d_in[5];
    const float* g1  = (const float*)d_in[6];
    const float* be1 = (const float*)d_in[7];
    const float* Ws2 = (const float*)d_in[8];
    const float* Wn2 = (const float*)d_in[9];
    const float* b2  = (const float*)d_in[10];
    const float* g2  = (const float*)d_in[11];
    const float* be2 = (const float*)d_in[12];
    const float* Ws3 = (const float*)d_in[13];
    const float* Wn3 = (const float*)d_in[14];
    const float* b3  = (const float*)d_in[15];
    float* out = (float*)d_out;

    char* p = (char*)d_ws;
    auto alloc = [&](size_t bytes) -> char* {
        char* r = p;
        p += (bytes + 255) & ~(size_t)255;
        return r;
    };
    float* hn   = (float*)alloc((size_t)N_NODES * D * 4);
    unsigned short* xb   = (unsigned short*)alloc((size_t)N_NODES * D * 2);
    unsigned short* h1hi = (unsigned short*)alloc((size_t)N_NODES * D * 2);
    unsigned short* h1lo = (unsigned short*)alloc((size_t)N_NODES * D * 2);
    unsigned short* h2hi = (unsigned short*)alloc((size_t)N_NODES * D * 2);
    unsigned short* h2lo = (unsigned short*)alloc((size_t)N_NODES * D * 2);
    int*   csr    = (int*)alloc((size_t)NEDGE * 4);
    int*   offs   = (int*)alloc((size_t)(N_NODES + 1) * 4);
    int*   cursor = (int*)alloc((size_t)N_NODES * 4);
    int*   degi   = (int*)alloc((size_t)N_NODES * 4);
    float* invdeg = (float*)alloc((size_t)N_NODES * 4);
    int*   bsum   = (int*)alloc(1024);
    float* sums   = (float*)alloc(256 * 4);
    float* scale  = (float*)alloc(128 * 4);
    float* shift  = (float*)alloc(128 * 4);
    unsigned short* wt = (unsigned short*)alloc((size_t)6 * 32768 * 2);

    const int NB_E = (NEDGE + 255) / 256;
    const int NB_N = (N_NODES + 255) / 256;
    const int NB_A = (N_NODES + 15) / 16;
    const int NB_T = (N_NODES * D / 8 + 255) / 256;

    const unsigned short* WsT1 = wt + 0 * 32768;
    const unsigned short* WnT1 = wt + 1 * 32768;
    const unsigned short* WsT2 = wt + 2 * 32768;
    const unsigned short* WnT2 = wt + 3 * 32768;
    const unsigned short* WsT3 = wt + 4 * 32768;
    const unsigned short* WnT3 = wt + 5 * 32768;

    // ---- weight prep + CSR build + x->bf16 (once) ----
    k_wprep<<<384, 256, 0, stream>>>(Ws1, Wn1, Ws2, Wn2, Ws3, Wn3, wt);
    hipMemsetAsync(degi, 0, (size_t)N_NODES * 4, stream);
    k_deg<<<NB_E, 256, 0, stream>>>(dst, degi);
    k_scan1<<<NB_N, 256, 0, stream>>>(degi, offs, bsum);
    k_scan2<<<1, 256, 0, stream>>>(bsum, NB_N);
    k_scan3<<<NB_N, 256, 0, stream>>>(degi, bsum, offs, cursor, invdeg);
    k_fill<<<NB_E, 256, 0, stream>>>(src, dst, cursor, csr);
    k_tobf16<<<NB_T, 256, 0, stream>>>(x, xb);

    // ---- Layer 1 ----
    k_agg<<<NB_A, 256, 0, stream>>>(xb, offs, csr, invdeg, scale, shift, 0, hn);
    hipMemsetAsync(sums, 0, 256 * 4, stream);
    k_mm<<<NB_MM, 256, 0, stream>>>(x, h1hi, h1lo, hn, WsT1, WnT1, b1, scale, shift,
                                    0, out, h1hi, h1lo, 0, 1, sums);
    k_bnfin<<<1, 128, 0, stream>>>(sums, g1, be1, scale, shift);

    // ---- Layer 2 (BN1+ReLU applied on read) ----
    k_agg<<<NB_A, 256, 0, stream>>>(h1hi, offs, csr, invdeg, scale, shift, 1, hn);
    hipMemsetAsync(sums, 0, 256 * 4, stream);
    k_mm<<<NB_MM, 256, 0, stream>>>(x, h1hi, h1lo, hn, WsT2, WnT2, b2, scale, shift,
                                    1, out, h2hi, h2lo, 0, 1, sums);
    k_bnfin<<<1, 128, 0, stream>>>(sums, g2, be2, scale, shift);

    // ---- Layer 3 (BN2+ReLU applied on read, fp32 out, no stats) ----
    k_agg<<<NB_A, 256, 0, stream>>>(h2hi, offs, csr, invdeg, scale, shift, 1, hn);
    k_mm<<<NB_MM, 256, 0, stream>>>(x, h2hi, h2lo, hn, WsT3, WnT3, b3, scale, shift,
                                    1, out, h1hi, h1lo, 1, 0, sums);
}